// Round 9
// baseline (377.823 us; speedup 1.0000x reference)
//
#include <hip/hip_runtime.h>
#include <math.h>

#define NN 100000
#define NE 1600000
#define NPB 256                     // nodes per bucket (dst >> 8)
#define NB 391                      // ceil(NN / NPB)
#define NCHUNK 256                  // binning chunks
#define CH ((NE + NCHUNK - 1) / NCHUNK)  // 6250 edges per chunk
#define LOG2E 1.44269504088896f

__device__ __forceinline__ float lrelu(float x) { return fmaxf(x, 0.2f * x); }
__device__ __forceinline__ float elu1(float x) { return x > 0.f ? x : (__expf(x) - 1.f); }
__device__ __forceinline__ float fexp2(float x) {
#if __has_builtin(__builtin_amdgcn_exp2f)
    return __builtin_amdgcn_exp2f(x);
#else
    return exp2f(x);
#endif
}
__device__ __forceinline__ unsigned bf16rne(float f) {
    unsigned u = __float_as_uint(f);
    return (u + 0x7FFFu + ((u >> 16) & 1u)) >> 16;
}
__device__ __forceinline__ float bf16lo(unsigned u) { return __uint_as_float(u << 16); }
__device__ __forceinline__ float bf16hi(unsigned u) {
    return __uint_as_float(u & 0xFFFF0000u);
}

// ================= binned CSR build =================
__global__ void __launch_bounds__(256) k_binA0(const int* __restrict__ dst,
                                               int* __restrict__ bucket_cnt) {
    __shared__ int hist[NB];
    int t = threadIdx.x;
    for (int b = t; b < NB; b += 256) hist[b] = 0;
    __syncthreads();
    int c0 = blockIdx.x * CH, c1 = min(NE, c0 + CH);
    for (int e = c0 + t; e < c1; e += 256) atomicAdd(&hist[dst[e] >> 8], 1);
    __syncthreads();
    for (int b = t; b < NB; b += 256)
        if (hist[b]) atomicAdd(&bucket_cnt[b], hist[b]);
}

__global__ void k_bscan(const int* __restrict__ bucket_cnt, int* __restrict__ bucket_base,
                        int* __restrict__ bucket_tail) {
    __shared__ int s[512];
    int t = threadIdx.x;
    int v = (t < NB) ? bucket_cnt[t] : 0;
    s[t] = v;
    __syncthreads();
    for (int off = 1; off < 512; off <<= 1) {
        int x = (t >= off) ? s[t - off] : 0;
        __syncthreads();
        if (t >= off) s[t] += x;
        __syncthreads();
    }
    if (t < NB) {
        int ex = s[t] - v;
        bucket_base[t] = ex;
        bucket_tail[t] = ex;
        if (t == NB - 1) bucket_base[NB] = s[t];
    }
}

// A2: re-read chunk, reserve per-bucket space, write bucket-grouped 8B records
__global__ void __launch_bounds__(256) k_binA2(const int* __restrict__ src,
                                               const int* __restrict__ dst,
                                               const float* __restrict__ ea,
                                               int* __restrict__ bucket_tail,
                                               uint2* __restrict__ binned,
                                               unsigned char* __restrict__ dstb) {
    __shared__ int hist[NB], base_l[NB], cursor[NB];
    int t = threadIdx.x;
    for (int b = t; b < NB; b += 256) {
        hist[b] = 0;
        cursor[b] = 0;
    }
    __syncthreads();
    int c0 = blockIdx.x * CH, c1 = min(NE, c0 + CH);
    for (int e = c0 + t; e < c1; e += 256) atomicAdd(&hist[dst[e] >> 8], 1);
    __syncthreads();
    for (int b = t; b < NB; b += 256)
        if (hist[b]) base_l[b] = atomicAdd(&bucket_tail[b], hist[b]);
    __syncthreads();
    for (int e = c0 + t; e < c1; e += 256) {
        int d = dst[e];
        int bkt = d >> 8;
        int idx = atomicAdd(&cursor[bkt], 1);
        int pos = base_l[bkt] + idx;
        unsigned pk = bf16rne(ea[2 * e]) | (bf16rne(ea[2 * e + 1]) << 16);
        binned[pos] = make_uint2((unsigned)src[e], pk);
        dstb[pos] = (unsigned char)(d & 255);
    }
}

// B: workgroup per bucket -> rowptr + final dst-sorted CSR + fused self-loop la
__global__ void __launch_bounds__(256) k_binB(const int* __restrict__ bucket_base,
                                              const uint2* __restrict__ binned,
                                              const unsigned char* __restrict__ dstb,
                                              int* __restrict__ rowptr,
                                              uint2* __restrict__ edges,
                                              float* __restrict__ la) {
    __shared__ int hist[NPB], pre[NPB], cursor[NPB];
    __shared__ float ea0s[NPB], ea1s[NPB];
    int b = blockIdx.x, t = threadIdx.x;
    int bb = bucket_base[b], be = bucket_base[b + 1];
    int nb0 = b << 8;
    hist[t] = 0;
    ea0s[t] = 0.f;
    ea1s[t] = 0.f;
    __syncthreads();
    for (int e = bb + t; e < be; e += 256) atomicAdd(&hist[dstb[e]], 1);
    __syncthreads();
    int v = hist[t];
    pre[t] = v;
    __syncthreads();
    for (int off = 1; off < 256; off <<= 1) {
        int x = (t >= off) ? pre[t - off] : 0;
        __syncthreads();
        if (t >= off) pre[t] += x;
        __syncthreads();
    }
    int ex = pre[t] - v;
    if (nb0 + t <= NN) rowptr[nb0 + t] = bb + ex;
    cursor[t] = bb + ex;
    __syncthreads();
    for (int e = bb + t; e < be; e += 256) {
        uint2 rec = binned[e];
        unsigned char d = dstb[e];
        int pos = atomicAdd(&cursor[d], 1);
        edges[pos] = rec;
        atomicAdd(&ea0s[d], bf16lo(rec.y));
        atomicAdd(&ea1s[d], bf16hi(rec.y));
    }
    __syncthreads();
    int n = nb0 + t;
    if (n < NN) {
        float dg = fmaxf((float)v, 1.0f);
        la[2 * n] = ea0s[t] / dg;
        la[2 * n + 1] = ea1s[t] / dg;
    }
}

// ---------- fused constants: me1[8], me2[4], me3[2] (at cbuf+12), vsd[40] (cbuf+16) ----------
__global__ void k_const(const float* __restrict__ We1, const float* __restrict__ aE1,
                        const float* __restrict__ We2, const float* __restrict__ aE2,
                        const float* __restrict__ We3, const float* __restrict__ aE3,
                        const float* __restrict__ W1, const float* __restrict__ aS1,
                        const float* __restrict__ aD1, float* __restrict__ cbuf) {
    int t = threadIdx.x;
    if (t < 8) {  // me1: d = t/4, hd = t%4
        int d = t >> 2, hd = t & 3;
        float s = 0.f;
        for (int c = 0; c < 32; c++) s += We1[d * 128 + hd * 32 + c] * aE1[hd * 32 + c];
        cbuf[t] = s * LOG2E;
    } else if (t < 12) {  // me2: idx = t-8, d = idx/2, hd = idx%2
        int idx = t - 8, d = idx >> 1, hd = idx & 1;
        float s = 0.f;
        for (int c = 0; c < 32; c++) s += We2[d * 64 + hd * 32 + c] * aE2[hd * 32 + c];
        cbuf[t] = s * LOG2E;
    } else if (t < 14) {  // me3: d = t-12
        cbuf[t] = We3[t - 12] * aE3[0] * LOG2E;
    } else if (t >= 16 && t < 56) {  // vsd[t-16]
        int r = (t - 16) % 20, hd = r / 5, i = r % 5;
        const float* a = (t - 16 < 20) ? aS1 : aD1;
        float s = 0.f;
        for (int c = 0; c < 32; c++) s += W1[i * 128 + hd * 32 + c] * a[hd * 32 + c];
        cbuf[t] = s * LOG2E;
    }
}

// layer-1 per-node: padded x + logits als1/ald1 (scaled)
__global__ void k_prep1(const float* __restrict__ x, const float* __restrict__ vsd,
                        float4* __restrict__ xp, float4* __restrict__ als1,
                        float4* __restrict__ ald1) {
    int n = blockIdx.x * blockDim.x + threadIdx.x;
    if (n >= NN) return;
    float x0 = x[5 * n], x1 = x[5 * n + 1], x2 = x[5 * n + 2], x3 = x[5 * n + 3],
          x4 = x[5 * n + 4];
    xp[2 * n] = make_float4(x0, x1, x2, x3);
    xp[2 * n + 1] = make_float4(x4, 0.f, 0.f, 0.f);
    float sv[4], dv[4];
#pragma unroll
    for (int hd = 0; hd < 4; hd++) {
        const float* vS = vsd + hd * 5;
        const float* vD = vsd + 20 + hd * 5;
        sv[hd] = x0 * vS[0] + x1 * vS[1] + x2 * vS[2] + x3 * vS[3] + x4 * vS[4];
        dv[hd] = x0 * vD[0] + x1 * vD[1] + x2 * vD[2] + x3 * vD[3] + x4 * vD[4];
    }
    als1[n] = make_float4(sv[0], sv[1], sv[2], sv[3]);
    ald1[n] = make_float4(dv[0], dv[1], dv[2], dv[3]);
}

// ---------- layer 1 agg: thread per (node, head); single pass, m = aself ----------
__global__ void k_agg1(const int* __restrict__ rowptr, const uint2* __restrict__ edges,
                       const float4* __restrict__ xp, const float* __restrict__ als1,
                       const float* __restrict__ ald1, const float* __restrict__ la,
                       const float* __restrict__ me, float* __restrict__ xw) {
    int t = blockIdx.x * blockDim.x + threadIdx.x;
    if (t >= NN * 4) return;
    int n = t >> 2, hd = t & 3;
    float me0 = me[hd], me1 = me[4 + hd];
    float aldn = ald1[t];
    float aself = lrelu(als1[t] + aldn + la[2 * n] * me0 + la[2 * n + 1] * me1);
    int start = rowptr[n], end = rowptr[n + 1];
    float den = 1.f;
    float4 xa = xp[2 * n];
    float xb = xp[2 * n + 1].x;
    float a0 = xa.x, a1 = xa.y, a2 = xa.z, a3 = xa.w, a4 = xb;
    for (int e = start; e < end; ++e) {
        uint2 ep = edges[e];
        int s = (int)ep.x;
        float a = lrelu(als1[s * 4 + hd] + aldn + bf16lo(ep.y) * me0 + bf16hi(ep.y) * me1);
        float p = fexp2(a - aself);
        den += p;
        float4 sa = xp[2 * s];
        float sb = xp[2 * s + 1].x;
        a0 += p * sa.x;
        a1 += p * sa.y;
        a2 += p * sa.z;
        a3 += p * sa.w;
        a4 += p * sb;
    }
    float r = 1.f / den;
    float* w = xw + (size_t)n * 20 + hd * 5;
    w[0] = a0 * r;
    w[1] = a1 * r;
    w[2] = a2 * r;
    w[3] = a3 * r;
    w[4] = a4 * r;
}

// ---------- layer 2 transform: tile GEMM, 32 nodes/block (16.9 KB LDS) ----------
__global__ void __launch_bounds__(256) k_l2trans(
        const float* __restrict__ xw, const float* __restrict__ W1,
        const float* __restrict__ b1, const float* __restrict__ W2,
        const float* __restrict__ aS2, const float* __restrict__ aD2,
        unsigned short* __restrict__ h2q, float* __restrict__ als2,
        float* __restrict__ ald2) {
    __shared__ float sx[32 * 132];
    int nb = blockIdx.x * 32, t = threadIdx.x;
    // phase 1: reconstruct act1 = elu(xw @ W1 + b1); 8 threads/node x 16 ch
    {
        int nl = t >> 3, q = t & 7;
        int node = nb + nl;
        float w[20];
        if (node < NN) {
#pragma unroll
            for (int i = 0; i < 20; i++) w[i] = xw[(size_t)node * 20 + i];
        } else {
#pragma unroll
            for (int i = 0; i < 20; i++) w[i] = 0.f;
        }
#pragma unroll
        for (int k = 0; k < 16; k++) {
            int ch = q + 8 * k;
            int hd = ch >> 5;
            float v = w[hd * 5] * W1[ch] + w[hd * 5 + 1] * W1[128 + ch] +
                      w[hd * 5 + 2] * W1[256 + ch] + w[hd * 5 + 3] * W1[384 + ch] +
                      w[hd * 5 + 4] * W1[512 + ch] + b1[ch];
            sx[nl * 132 + ch] = (node < NN) ? elu1(v) : 0.f;
        }
    }
    __syncthreads();
    // phase 2: h2 = act1 @ W2 (M=32, K=128, N=64); thread = 2 nodes x 4 cols
    int jq = t & 15, ng = t >> 4;
    int j4 = jq * 4;
    float4 acc[2];
#pragma unroll
    for (int p = 0; p < 2; p++) acc[p] = make_float4(0.f, 0.f, 0.f, 0.f);
    for (int ic = 0; ic < 128; ic += 4) {
        float4 s[2];
#pragma unroll
        for (int p = 0; p < 2; p++)
            s[p] = *(const float4*)(sx + (ng * 2 + p) * 132 + ic);
#pragma unroll
        for (int r = 0; r < 4; r++) {
            float4 wv = *(const float4*)(W2 + (ic + r) * 64 + j4);
#pragma unroll
            for (int p = 0; p < 2; p++) {
                float sv = (r == 0) ? s[p].x : (r == 1) ? s[p].y : (r == 2) ? s[p].z : s[p].w;
                acc[p].x += sv * wv.x;
                acc[p].y += sv * wv.y;
                acc[p].z += sv * wv.z;
                acc[p].w += sv * wv.w;
            }
        }
    }
    int hd = jq >> 3;
    float4 a_s = *(const float4*)(aS2 + j4);
    float4 a_d = *(const float4*)(aD2 + j4);
    float pS[2], pD[2];
#pragma unroll
    for (int p = 0; p < 2; p++) {
        pS[p] = acc[p].x * a_s.x + acc[p].y * a_s.y + acc[p].z * a_s.z + acc[p].w * a_s.w;
        pD[p] = acc[p].x * a_d.x + acc[p].y * a_d.y + acc[p].z * a_d.z + acc[p].w * a_d.w;
    }
#pragma unroll
    for (int off = 1; off < 8; off <<= 1) {
#pragma unroll
        for (int p = 0; p < 2; p++) {
            pS[p] += __shfl_xor(pS[p], off);
            pD[p] += __shfl_xor(pD[p], off);
        }
    }
#pragma unroll
    for (int p = 0; p < 2; p++) {
        int node = nb + ng * 2 + p;
        if (node < NN) {
            ushort4 q;
            q.x = (unsigned short)bf16rne(acc[p].x);
            q.y = (unsigned short)bf16rne(acc[p].y);
            q.z = (unsigned short)bf16rne(acc[p].z);
            q.w = (unsigned short)bf16rne(acc[p].w);
            *(ushort4*)(h2q + (size_t)node * 64 + j4) = q;
            if ((jq & 7) == 0) {
                als2[node * 2 + hd] = pS[p] * LOG2E;
                ald2[node * 2 + hd] = pD[p] * LOG2E;
            }
        }
    }
}

// ---------- layer 2 agg: thread per (node, head-half); single pass, m = aself ----------
__global__ void k_agg2(const int* __restrict__ rowptr, const uint2* __restrict__ edges,
                       const unsigned short* __restrict__ h2q,
                       const float* __restrict__ als2, const float* __restrict__ ald2,
                       const float* __restrict__ la, const float* __restrict__ me,
                       const float* __restrict__ b2, const float* __restrict__ W3,
                       float* __restrict__ h3) {
    int t = blockIdx.x * blockDim.x + threadIdx.x;
    if (t >= NN * 4) return;
    int n = t >> 2, sub = t & 3, hd = sub >> 1, qh = sub & 1;
    int cbase = hd * 32 + qh * 16;
    float me0 = me[hd], me1 = me[2 + hd];
    float aldn = ald2[n * 2 + hd];
    float aself = lrelu(als2[n * 2 + hd] + aldn + la[2 * n] * me0 + la[2 * n + 1] * me1);
    int start = rowptr[n], end = rowptr[n + 1];
    float den = 1.f;
    float acc[16];
    {
        const uint4* hp = (const uint4*)(h2q + (size_t)n * 64 + cbase);
        uint4 u0 = hp[0], u1 = hp[1];
        acc[0] = bf16lo(u0.x); acc[1] = bf16hi(u0.x);
        acc[2] = bf16lo(u0.y); acc[3] = bf16hi(u0.y);
        acc[4] = bf16lo(u0.z); acc[5] = bf16hi(u0.z);
        acc[6] = bf16lo(u0.w); acc[7] = bf16hi(u0.w);
        acc[8] = bf16lo(u1.x); acc[9] = bf16hi(u1.x);
        acc[10] = bf16lo(u1.y); acc[11] = bf16hi(u1.y);
        acc[12] = bf16lo(u1.z); acc[13] = bf16hi(u1.z);
        acc[14] = bf16lo(u1.w); acc[15] = bf16hi(u1.w);
    }
    for (int e = start; e < end; ++e) {
        uint2 ep = edges[e];
        int s = (int)ep.x;
        float a = lrelu(als2[s * 2 + hd] + aldn + bf16lo(ep.y) * me0 + bf16hi(ep.y) * me1);
        float p = fexp2(a - aself);
        den += p;
        const uint4* sp = (const uint4*)(h2q + (size_t)s * 64 + cbase);
        uint4 u0 = sp[0], u1 = sp[1];
        acc[0] += p * bf16lo(u0.x); acc[1] += p * bf16hi(u0.x);
        acc[2] += p * bf16lo(u0.y); acc[3] += p * bf16hi(u0.y);
        acc[4] += p * bf16lo(u0.z); acc[5] += p * bf16hi(u0.z);
        acc[6] += p * bf16lo(u0.w); acc[7] += p * bf16hi(u0.w);
        acc[8] += p * bf16lo(u1.x); acc[9] += p * bf16hi(u1.x);
        acc[10] += p * bf16lo(u1.y); acc[11] += p * bf16hi(u1.y);
        acc[12] += p * bf16lo(u1.z); acc[13] += p * bf16hi(u1.z);
        acc[14] += p * bf16lo(u1.w); acc[15] += p * bf16hi(u1.w);
    }
    float r = 1.f / den;
    float part = 0.f;
#pragma unroll
    for (int c = 0; c < 16; c++) {
        float v = elu1(acc[c] * r + b2[cbase + c]);
        part += v * W3[cbase + c];
    }
    part += __shfl_xor(part, 1);
    part += __shfl_xor(part, 2);
    if (sub == 0) h3[n] = part;
}

// ---------- layer 3 agg: wave per node, lanes over edges; m = aself ----------
__global__ void k_agg3(const int* __restrict__ rowptr, const uint2* __restrict__ edges,
                       const float* __restrict__ h, const float* __restrict__ aS3,
                       const float* __restrict__ aD3, const float* __restrict__ la,
                       const float* __restrict__ me, const float* __restrict__ b,
                       float* __restrict__ out) {
    int n = (blockIdx.x * blockDim.x + threadIdx.x) >> 6;
    if (n >= NN) return;
    int lane = threadIdx.x & 63;
    float me0 = me[0], me1 = me[1];
    float aSs = aS3[0] * LOG2E, aDs = aD3[0] * LOG2E;
    float hn = h[n];
    float ald_n = hn * aDs;
    float aself = lrelu(hn * aSs + ald_n + la[2 * n] * me0 + la[2 * n + 1] * me1);
    int start = rowptr[n], end = rowptr[n + 1];
    float den = 0.f, num = 0.f;
    for (int e = start + lane; e < end; e += 64) {
        uint2 ep = edges[e];
        int s = (int)ep.x;
        float hv = h[s];
        float a = lrelu(hv * aSs + ald_n + bf16lo(ep.y) * me0 + bf16hi(ep.y) * me1);
        float p = fexp2(a - aself);
        den += p;
        num += p * hv;
    }
#pragma unroll
    for (int off = 32; off > 0; off >>= 1) {
        den += __shfl_xor(den, off);
        num += __shfl_xor(num, off);
    }
    if (lane == 0) {
        den += 1.f;
        num += hn;
        float v = num / den + b[0];
        out[n] = 1.f / (1.f + __expf(-v));
    }
}

extern "C" void kernel_launch(void* const* d_in, const int* in_sizes, int n_in,
                              void* d_out, int out_size, void* d_ws, size_t ws_size,
                              hipStream_t stream) {
    const float* x   = (const float*)d_in[0];
    const int*   ei  = (const int*)d_in[1];
    const float* ea  = (const float*)d_in[2];
    const float* W1  = (const float*)d_in[3];
    const float* aS1 = (const float*)d_in[4];
    const float* aD1 = (const float*)d_in[5];
    const float* We1 = (const float*)d_in[6];
    const float* aE1 = (const float*)d_in[7];
    const float* b1  = (const float*)d_in[8];
    const float* W2  = (const float*)d_in[9];
    const float* aS2 = (const float*)d_in[10];
    const float* aD2 = (const float*)d_in[11];
    const float* We2 = (const float*)d_in[12];
    const float* aE2 = (const float*)d_in[13];
    const float* b2  = (const float*)d_in[14];
    const float* W3  = (const float*)d_in[15];
    const float* aS3 = (const float*)d_in[16];
    const float* aD3 = (const float*)d_in[17];
    const float* We3 = (const float*)d_in[18];
    const float* aE3 = (const float*)d_in[19];
    const float* b3  = (const float*)d_in[20];

    const int* srcv = ei;
    const int* dstv = ei + NE;

    char* basep = (char*)d_ws;
    size_t off = 0;
    auto alloc = [&](size_t nbytes) -> void* {
        void* p = basep + off;
        off += (nbytes + 255) & ~(size_t)255;
        return p;
    };
    int*    bucket_cnt  = (int*)alloc((size_t)(NB + 1) * 4);
    int*    bucket_base = (int*)alloc((size_t)(NB + 1) * 4);
    int*    bucket_tail = (int*)alloc((size_t)(NB + 1) * 4);
    int*    rowptr      = (int*)alloc((size_t)(NN + 1) * 4);
    uint2*  binned      = (uint2*)alloc((size_t)NE * 8);
    unsigned char* dstb = (unsigned char*)alloc((size_t)NE);
    uint2*  edges       = (uint2*)alloc((size_t)NE * 8);
    float*  la          = (float*)alloc((size_t)NN * 8);
    float*  cbuf        = (float*)alloc(256);   // me1[0..7], me2[8..11], me3[12..13], vsd[16..55]
    float4* xp          = (float4*)alloc((size_t)NN * 32);
    float4* als1        = (float4*)alloc((size_t)NN * 16);
    float4* ald1        = (float4*)alloc((size_t)NN * 16);
    float*  xw          = (float*)alloc((size_t)NN * 80);
    unsigned short* h2q = (unsigned short*)alloc((size_t)NN * 128);
    float*  als2        = (float*)alloc((size_t)NN * 8);
    float*  ald2        = (float*)alloc((size_t)NN * 8);
    float*  h3          = (float*)alloc((size_t)NN * 4);
    (void)ws_size; (void)in_sizes; (void)n_in; (void)out_size;

    float* me1 = cbuf;
    float* me2 = cbuf + 8;
    float* me3 = cbuf + 12;
    float* vsd = cbuf + 16;

    auto cdiv = [](long long a, long long b) { return (int)((a + b - 1) / b); };
    const int BS = 256;

    // ---- binned CSR build (la fused into binB) ----
    hipMemsetAsync(bucket_cnt, 0, (size_t)(NB + 1) * 4, stream);
    k_binA0<<<NCHUNK, 256, 0, stream>>>(dstv, bucket_cnt);
    k_bscan<<<1, 512, 0, stream>>>(bucket_cnt, bucket_base, bucket_tail);
    k_binA2<<<NCHUNK, 256, 0, stream>>>(srcv, dstv, ea, bucket_tail, binned, dstb);
    k_binB<<<NB, 256, 0, stream>>>(bucket_base, binned, dstb, rowptr, edges, la);

    // ---- all tiny constants in one launch ----
    k_const<<<1, 64, 0, stream>>>(We1, aE1, We2, aE2, We3, aE3, W1, aS1, aD1, cbuf);

    // ================= Layer 1: IN=5, H=4, C=32 (ELU) =================
    k_prep1<<<cdiv(NN, BS), BS, 0, stream>>>(x, vsd, xp, als1, ald1);
    k_agg1<<<cdiv((long long)NN * 4, BS), BS, 0, stream>>>(rowptr, edges, xp,
                                                           (const float*)als1,
                                                           (const float*)ald1, la, me1, xw);

    // ================= Layer 2: IN=128, H=2, C=32 (ELU) =================
    k_l2trans<<<cdiv(NN, 32), 256, 0, stream>>>(xw, W1, b1, W2, aS2, aD2, h2q, als2, ald2);
    k_agg2<<<cdiv((long long)NN * 4, BS), BS, 0, stream>>>(rowptr, edges, h2q, als2, ald2,
                                                           la, me2, b2, W3, h3);

    // ================= Layer 3: IN=64, H=1, C=1 (sigmoid) =================
    k_agg3<<<cdiv(NN, 4), 256, 0, stream>>>(rowptr, edges, h3, aS3, aD3, la, me3,
                                            b3, (float*)d_out);
}

// Round 10
// 344.786 us; speedup vs baseline: 1.0958x; 1.0958x over previous
//
#include <hip/hip_runtime.h>
#include <math.h>

#define NN 100000
#define NE 1600000
#define NPB 256                     // nodes per bucket (dst >> 8)
#define NB 391                      // ceil(NN / NPB)
#define NCHUNK 256                  // binning chunks
#define CH ((NE + NCHUNK - 1) / NCHUNK)  // 6250 edges per chunk
#define LOG2E 1.44269504088896f

__device__ __forceinline__ float lrelu(float x) { return fmaxf(x, 0.2f * x); }
__device__ __forceinline__ float elu1(float x) { return x > 0.f ? x : (__expf(x) - 1.f); }
__device__ __forceinline__ float fexp2(float x) {
#if __has_builtin(__builtin_amdgcn_exp2f)
    return __builtin_amdgcn_exp2f(x);
#else
    return exp2f(x);
#endif
}
__device__ __forceinline__ unsigned bf16rne(float f) {
    unsigned u = __float_as_uint(f);
    return (u + 0x7FFFu + ((u >> 16) & 1u)) >> 16;
}
__device__ __forceinline__ float bf16lo(unsigned u) { return __uint_as_float(u << 16); }
__device__ __forceinline__ float bf16hi(unsigned u) {
    return __uint_as_float(u & 0xFFFF0000u);
}

// ================= binned CSR build =================
__global__ void __launch_bounds__(256) k_binA0(const int* __restrict__ dst,
                                               int* __restrict__ bucket_cnt) {
    __shared__ int hist[NB];
    int t = threadIdx.x;
    for (int b = t; b < NB; b += 256) hist[b] = 0;
    __syncthreads();
    int c0 = blockIdx.x * CH, c1 = min(NE, c0 + CH);
    for (int e = c0 + t; e < c1; e += 256) atomicAdd(&hist[dst[e] >> 8], 1);
    __syncthreads();
    for (int b = t; b < NB; b += 256)
        if (hist[b]) atomicAdd(&bucket_cnt[b], hist[b]);
}

__global__ void k_bscan(const int* __restrict__ bucket_cnt, int* __restrict__ bucket_base,
                        int* __restrict__ bucket_tail) {
    __shared__ int s[512];
    int t = threadIdx.x;
    int v = (t < NB) ? bucket_cnt[t] : 0;
    s[t] = v;
    __syncthreads();
    for (int off = 1; off < 512; off <<= 1) {
        int x = (t >= off) ? s[t - off] : 0;
        __syncthreads();
        if (t >= off) s[t] += x;
        __syncthreads();
    }
    if (t < NB) {
        int ex = s[t] - v;
        bucket_base[t] = ex;
        bucket_tail[t] = ex;
        if (t == NB - 1) bucket_base[NB] = s[t];
    }
}

// A2: re-read chunk, reserve per-bucket space, write bucket-grouped 8B records
__global__ void __launch_bounds__(256) k_binA2(const int* __restrict__ src,
                                               const int* __restrict__ dst,
                                               const float* __restrict__ ea,
                                               int* __restrict__ bucket_tail,
                                               uint2* __restrict__ binned,
                                               unsigned char* __restrict__ dstb) {
    __shared__ int hist[NB], base_l[NB], cursor[NB];
    int t = threadIdx.x;
    for (int b = t; b < NB; b += 256) {
        hist[b] = 0;
        cursor[b] = 0;
    }
    __syncthreads();
    int c0 = blockIdx.x * CH, c1 = min(NE, c0 + CH);
    for (int e = c0 + t; e < c1; e += 256) atomicAdd(&hist[dst[e] >> 8], 1);
    __syncthreads();
    for (int b = t; b < NB; b += 256)
        if (hist[b]) base_l[b] = atomicAdd(&bucket_tail[b], hist[b]);
    __syncthreads();
    for (int e = c0 + t; e < c1; e += 256) {
        int d = dst[e];
        int bkt = d >> 8;
        int idx = atomicAdd(&cursor[bkt], 1);
        int pos = base_l[bkt] + idx;
        unsigned pk = bf16rne(ea[2 * e]) | (bf16rne(ea[2 * e + 1]) << 16);
        binned[pos] = make_uint2((unsigned)src[e], pk);
        dstb[pos] = (unsigned char)(d & 255);
    }
}

// B: workgroup per bucket -> rowptr + final dst-sorted CSR + fused self-loop la
__global__ void __launch_bounds__(256) k_binB(const int* __restrict__ bucket_base,
                                              const uint2* __restrict__ binned,
                                              const unsigned char* __restrict__ dstb,
                                              int* __restrict__ rowptr,
                                              uint2* __restrict__ edges,
                                              float* __restrict__ la) {
    __shared__ int hist[NPB], pre[NPB], cursor[NPB];
    __shared__ float ea0s[NPB], ea1s[NPB];
    int b = blockIdx.x, t = threadIdx.x;
    int bb = bucket_base[b], be = bucket_base[b + 1];
    int nb0 = b << 8;
    hist[t] = 0;
    ea0s[t] = 0.f;
    ea1s[t] = 0.f;
    __syncthreads();
    for (int e = bb + t; e < be; e += 256) atomicAdd(&hist[dstb[e]], 1);
    __syncthreads();
    int v = hist[t];
    pre[t] = v;
    __syncthreads();
    for (int off = 1; off < 256; off <<= 1) {
        int x = (t >= off) ? pre[t - off] : 0;
        __syncthreads();
        if (t >= off) pre[t] += x;
        __syncthreads();
    }
    int ex = pre[t] - v;
    if (nb0 + t <= NN) rowptr[nb0 + t] = bb + ex;
    cursor[t] = bb + ex;
    __syncthreads();
    for (int e = bb + t; e < be; e += 256) {
        uint2 rec = binned[e];
        unsigned char d = dstb[e];
        int pos = atomicAdd(&cursor[d], 1);
        edges[pos] = rec;
        atomicAdd(&ea0s[d], bf16lo(rec.y));
        atomicAdd(&ea1s[d], bf16hi(rec.y));
    }
    __syncthreads();
    int n = nb0 + t;
    if (n < NN) {
        float dg = fmaxf((float)v, 1.0f);
        la[2 * n] = ea0s[t] / dg;
        la[2 * n + 1] = ea1s[t] / dg;
    }
}

// ---------- fused constants: me1[8], me2[4], me3[2] (at cbuf+12), vsd[40] (cbuf+16) ----------
__global__ void k_const(const float* __restrict__ We1, const float* __restrict__ aE1,
                        const float* __restrict__ We2, const float* __restrict__ aE2,
                        const float* __restrict__ We3, const float* __restrict__ aE3,
                        const float* __restrict__ W1, const float* __restrict__ aS1,
                        const float* __restrict__ aD1, float* __restrict__ cbuf) {
    int t = threadIdx.x;
    if (t < 8) {
        int d = t >> 2, hd = t & 3;
        float s = 0.f;
        for (int c = 0; c < 32; c++) s += We1[d * 128 + hd * 32 + c] * aE1[hd * 32 + c];
        cbuf[t] = s * LOG2E;
    } else if (t < 12) {
        int idx = t - 8, d = idx >> 1, hd = idx & 1;
        float s = 0.f;
        for (int c = 0; c < 32; c++) s += We2[d * 64 + hd * 32 + c] * aE2[hd * 32 + c];
        cbuf[t] = s * LOG2E;
    } else if (t < 14) {
        cbuf[t] = We3[t - 12] * aE3[0] * LOG2E;
    } else if (t >= 16 && t < 56) {
        int r = (t - 16) % 20, hd = r / 5, i = r % 5;
        const float* a = (t - 16 < 20) ? aS1 : aD1;
        float s = 0.f;
        for (int c = 0; c < 32; c++) s += W1[i * 128 + hd * 32 + c] * a[hd * 32 + c];
        cbuf[t] = s * LOG2E;
    }
}

// layer-1 per-node: padded x + logits als1/ald1 (scaled)
__global__ void k_prep1(const float* __restrict__ x, const float* __restrict__ vsd,
                        float4* __restrict__ xp, float4* __restrict__ als1,
                        float4* __restrict__ ald1) {
    int n = blockIdx.x * blockDim.x + threadIdx.x;
    if (n >= NN) return;
    float x0 = x[5 * n], x1 = x[5 * n + 1], x2 = x[5 * n + 2], x3 = x[5 * n + 3],
          x4 = x[5 * n + 4];
    xp[2 * n] = make_float4(x0, x1, x2, x3);
    xp[2 * n + 1] = make_float4(x4, 0.f, 0.f, 0.f);
    float sv[4], dv[4];
#pragma unroll
    for (int hd = 0; hd < 4; hd++) {
        const float* vS = vsd + hd * 5;
        const float* vD = vsd + 20 + hd * 5;
        sv[hd] = x0 * vS[0] + x1 * vS[1] + x2 * vS[2] + x3 * vS[3] + x4 * vS[4];
        dv[hd] = x0 * vD[0] + x1 * vD[1] + x2 * vD[2] + x3 * vD[3] + x4 * vD[4];
    }
    als1[n] = make_float4(sv[0], sv[1], sv[2], sv[3]);
    ald1[n] = make_float4(dv[0], dv[1], dv[2], dv[3]);
}

// ---------- layer 1 agg: thread per (node, head); single pass, m = aself ----------
__global__ void k_agg1(const int* __restrict__ rowptr, const uint2* __restrict__ edges,
                       const float4* __restrict__ xp, const float* __restrict__ als1,
                       const float* __restrict__ ald1, const float* __restrict__ la,
                       const float* __restrict__ me, float* __restrict__ xw) {
    int t = blockIdx.x * blockDim.x + threadIdx.x;
    if (t >= NN * 4) return;
    int n = t >> 2, hd = t & 3;
    float me0 = me[hd], me1 = me[4 + hd];
    float aldn = ald1[t];
    float aself = lrelu(als1[t] + aldn + la[2 * n] * me0 + la[2 * n + 1] * me1);
    int start = rowptr[n], end = rowptr[n + 1];
    float den = 1.f;
    float4 xa = xp[2 * n];
    float xb = xp[2 * n + 1].x;
    float a0 = xa.x, a1 = xa.y, a2 = xa.z, a3 = xa.w, a4 = xb;
    for (int e = start; e < end; ++e) {
        uint2 ep = edges[e];
        int s = (int)ep.x;
        float a = lrelu(als1[s * 4 + hd] + aldn + bf16lo(ep.y) * me0 + bf16hi(ep.y) * me1);
        float p = fexp2(a - aself);
        den += p;
        float4 sa = xp[2 * s];
        float sb = xp[2 * s + 1].x;
        a0 += p * sa.x;
        a1 += p * sa.y;
        a2 += p * sa.z;
        a3 += p * sa.w;
        a4 += p * sb;
    }
    float r = 1.f / den;
    float* w = xw + (size_t)n * 20 + hd * 5;
    w[0] = a0 * r;
    w[1] = a1 * r;
    w[2] = a2 * r;
    w[3] = a3 * r;
    w[4] = a4 * r;
}

// ---------- layer 2 transform: wave-sized tile GEMM (1 wave = 16 nodes, 8.4 KB LDS) ----------
// Per-thread work identical to the R8 64-node version (4 nodes x 4 cols): same
// load:FMA ratio, same conflict-free bank patterns, but ~16 independent blocks/CU.
__global__ void __launch_bounds__(64) k_l2trans(
        const float* __restrict__ xw, const float* __restrict__ W1,
        const float* __restrict__ b1, const float* __restrict__ W2,
        const float* __restrict__ aS2, const float* __restrict__ aD2,
        unsigned short* __restrict__ h2q, float* __restrict__ als2,
        float* __restrict__ ald2) {
    __shared__ float sx[16 * 132];
    int nb = blockIdx.x * 16, t = threadIdx.x;
    // phase 1: reconstruct act1 = elu(xw @ W1 + b1); 4 threads/node x 32 ch
    {
        int nl = t >> 2, q = t & 3;
        int node = nb + nl;
        float w[20];
        if (node < NN) {
#pragma unroll
            for (int i = 0; i < 20; i++) w[i] = xw[(size_t)node * 20 + i];
        } else {
#pragma unroll
            for (int i = 0; i < 20; i++) w[i] = 0.f;
        }
#pragma unroll
        for (int k = 0; k < 32; k++) {
            int ch = q + 4 * k;
            int hd = ch >> 5;
            float v = w[hd * 5] * W1[ch] + w[hd * 5 + 1] * W1[128 + ch] +
                      w[hd * 5 + 2] * W1[256 + ch] + w[hd * 5 + 3] * W1[384 + ch] +
                      w[hd * 5 + 4] * W1[512 + ch] + b1[ch];
            sx[nl * 132 + ch] = (node < NN) ? elu1(v) : 0.f;
        }
    }
    __syncthreads();
    // phase 2: h2 = act1 @ W2 (M=16, K=128, N=64); thread = 4 nodes x 4 cols
    int jq = t & 15, ng = t >> 4;
    int j4 = jq * 4;
    float4 acc[4];
#pragma unroll
    for (int p = 0; p < 4; p++) acc[p] = make_float4(0.f, 0.f, 0.f, 0.f);
    for (int ic = 0; ic < 128; ic += 4) {
        float4 s[4];
#pragma unroll
        for (int p = 0; p < 4; p++)
            s[p] = *(const float4*)(sx + (ng * 4 + p) * 132 + ic);
#pragma unroll
        for (int r = 0; r < 4; r++) {
            float4 wv = *(const float4*)(W2 + (ic + r) * 64 + j4);
#pragma unroll
            for (int p = 0; p < 4; p++) {
                float sv = (r == 0) ? s[p].x : (r == 1) ? s[p].y : (r == 2) ? s[p].z : s[p].w;
                acc[p].x += sv * wv.x;
                acc[p].y += sv * wv.y;
                acc[p].z += sv * wv.z;
                acc[p].w += sv * wv.w;
            }
        }
    }
    int hd = jq >> 3;
    float4 a_s = *(const float4*)(aS2 + j4);
    float4 a_d = *(const float4*)(aD2 + j4);
    float pS[4], pD[4];
#pragma unroll
    for (int p = 0; p < 4; p++) {
        pS[p] = acc[p].x * a_s.x + acc[p].y * a_s.y + acc[p].z * a_s.z + acc[p].w * a_s.w;
        pD[p] = acc[p].x * a_d.x + acc[p].y * a_d.y + acc[p].z * a_d.z + acc[p].w * a_d.w;
    }
#pragma unroll
    for (int off = 1; off < 8; off <<= 1) {
#pragma unroll
        for (int p = 0; p < 4; p++) {
            pS[p] += __shfl_xor(pS[p], off);
            pD[p] += __shfl_xor(pD[p], off);
        }
    }
#pragma unroll
    for (int p = 0; p < 4; p++) {
        int node = nb + ng * 4 + p;
        if (node < NN) {
            ushort4 q;
            q.x = (unsigned short)bf16rne(acc[p].x);
            q.y = (unsigned short)bf16rne(acc[p].y);
            q.z = (unsigned short)bf16rne(acc[p].z);
            q.w = (unsigned short)bf16rne(acc[p].w);
            *(ushort4*)(h2q + (size_t)node * 64 + j4) = q;
            if ((jq & 7) == 0) {
                als2[node * 2 + hd] = pS[p] * LOG2E;
                ald2[node * 2 + hd] = pD[p] * LOG2E;
            }
        }
    }
}

// ---------- layer 2 agg: thread per (node, head-half); single pass, m = aself ----------
__global__ void k_agg2(const int* __restrict__ rowptr, const uint2* __restrict__ edges,
                       const unsigned short* __restrict__ h2q,
                       const float* __restrict__ als2, const float* __restrict__ ald2,
                       const float* __restrict__ la, const float* __restrict__ me,
                       const float* __restrict__ b2, const float* __restrict__ W3,
                       float* __restrict__ h3) {
    int t = blockIdx.x * blockDim.x + threadIdx.x;
    if (t >= NN * 4) return;
    int n = t >> 2, sub = t & 3, hd = sub >> 1, qh = sub & 1;
    int cbase = hd * 32 + qh * 16;
    float me0 = me[hd], me1 = me[2 + hd];
    float aldn = ald2[n * 2 + hd];
    float aself = lrelu(als2[n * 2 + hd] + aldn + la[2 * n] * me0 + la[2 * n + 1] * me1);
    int start = rowptr[n], end = rowptr[n + 1];
    float den = 1.f;
    float acc[16];
    {
        const uint4* hp = (const uint4*)(h2q + (size_t)n * 64 + cbase);
        uint4 u0 = hp[0], u1 = hp[1];
        acc[0] = bf16lo(u0.x); acc[1] = bf16hi(u0.x);
        acc[2] = bf16lo(u0.y); acc[3] = bf16hi(u0.y);
        acc[4] = bf16lo(u0.z); acc[5] = bf16hi(u0.z);
        acc[6] = bf16lo(u0.w); acc[7] = bf16hi(u0.w);
        acc[8] = bf16lo(u1.x); acc[9] = bf16hi(u1.x);
        acc[10] = bf16lo(u1.y); acc[11] = bf16hi(u1.y);
        acc[12] = bf16lo(u1.z); acc[13] = bf16hi(u1.z);
        acc[14] = bf16lo(u1.w); acc[15] = bf16hi(u1.w);
    }
    for (int e = start; e < end; ++e) {
        uint2 ep = edges[e];
        int s = (int)ep.x;
        float a = lrelu(als2[s * 2 + hd] + aldn + bf16lo(ep.y) * me0 + bf16hi(ep.y) * me1);
        float p = fexp2(a - aself);
        den += p;
        const uint4* sp = (const uint4*)(h2q + (size_t)s * 64 + cbase);
        uint4 u0 = sp[0], u1 = sp[1];
        acc[0] += p * bf16lo(u0.x); acc[1] += p * bf16hi(u0.x);
        acc[2] += p * bf16lo(u0.y); acc[3] += p * bf16hi(u0.y);
        acc[4] += p * bf16lo(u0.z); acc[5] += p * bf16hi(u0.z);
        acc[6] += p * bf16lo(u0.w); acc[7] += p * bf16hi(u0.w);
        acc[8] += p * bf16lo(u1.x); acc[9] += p * bf16hi(u1.x);
        acc[10] += p * bf16lo(u1.y); acc[11] += p * bf16hi(u1.y);
        acc[12] += p * bf16lo(u1.z); acc[13] += p * bf16hi(u1.z);
        acc[14] += p * bf16lo(u1.w); acc[15] += p * bf16hi(u1.w);
    }
    float r = 1.f / den;
    float part = 0.f;
#pragma unroll
    for (int c = 0; c < 16; c++) {
        float v = elu1(acc[c] * r + b2[cbase + c]);
        part += v * W3[cbase + c];
    }
    part += __shfl_xor(part, 1);
    part += __shfl_xor(part, 2);
    if (sub == 0) h3[n] = part;
}

// ---------- layer 3 agg: wave per node, lanes over edges; m = aself ----------
__global__ void k_agg3(const int* __restrict__ rowptr, const uint2* __restrict__ edges,
                       const float* __restrict__ h, const float* __restrict__ aS3,
                       const float* __restrict__ aD3, const float* __restrict__ la,
                       const float* __restrict__ me, const float* __restrict__ b,
                       float* __restrict__ out) {
    int n = (blockIdx.x * blockDim.x + threadIdx.x) >> 6;
    if (n >= NN) return;
    int lane = threadIdx.x & 63;
    float me0 = me[0], me1 = me[1];
    float aSs = aS3[0] * LOG2E, aDs = aD3[0] * LOG2E;
    float hn = h[n];
    float ald_n = hn * aDs;
    float aself = lrelu(hn * aSs + ald_n + la[2 * n] * me0 + la[2 * n + 1] * me1);
    int start = rowptr[n], end = rowptr[n + 1];
    float den = 0.f, num = 0.f;
    for (int e = start + lane; e < end; e += 64) {
        uint2 ep = edges[e];
        int s = (int)ep.x;
        float hv = h[s];
        float a = lrelu(hv * aSs + ald_n + bf16lo(ep.y) * me0 + bf16hi(ep.y) * me1);
        float p = fexp2(a - aself);
        den += p;
        num += p * hv;
    }
#pragma unroll
    for (int off = 32; off > 0; off >>= 1) {
        den += __shfl_xor(den, off);
        num += __shfl_xor(num, off);
    }
    if (lane == 0) {
        den += 1.f;
        num += hn;
        float v = num / den + b[0];
        out[n] = 1.f / (1.f + __expf(-v));
    }
}

extern "C" void kernel_launch(void* const* d_in, const int* in_sizes, int n_in,
                              void* d_out, int out_size, void* d_ws, size_t ws_size,
                              hipStream_t stream) {
    const float* x   = (const float*)d_in[0];
    const int*   ei  = (const int*)d_in[1];
    const float* ea  = (const float*)d_in[2];
    const float* W1  = (const float*)d_in[3];
    const float* aS1 = (const float*)d_in[4];
    const float* aD1 = (const float*)d_in[5];
    const float* We1 = (const float*)d_in[6];
    const float* aE1 = (const float*)d_in[7];
    const float* b1  = (const float*)d_in[8];
    const float* W2  = (const float*)d_in[9];
    const float* aS2 = (const float*)d_in[10];
    const float* aD2 = (const float*)d_in[11];
    const float* We2 = (const float*)d_in[12];
    const float* aE2 = (const float*)d_in[13];
    const float* b2  = (const float*)d_in[14];
    const float* W3  = (const float*)d_in[15];
    const float* aS3 = (const float*)d_in[16];
    const float* aD3 = (const float*)d_in[17];
    const float* We3 = (const float*)d_in[18];
    const float* aE3 = (const float*)d_in[19];
    const float* b3  = (const float*)d_in[20];

    const int* srcv = ei;
    const int* dstv = ei + NE;

    char* basep = (char*)d_ws;
    size_t off = 0;
    auto alloc = [&](size_t nbytes) -> void* {
        void* p = basep + off;
        off += (nbytes + 255) & ~(size_t)255;
        return p;
    };
    int*    bucket_cnt  = (int*)alloc((size_t)(NB + 1) * 4);
    int*    bucket_base = (int*)alloc((size_t)(NB + 1) * 4);
    int*    bucket_tail = (int*)alloc((size_t)(NB + 1) * 4);
    int*    rowptr      = (int*)alloc((size_t)(NN + 1) * 4);
    uint2*  binned      = (uint2*)alloc((size_t)NE * 8);
    unsigned char* dstb = (unsigned char*)alloc((size_t)NE);
    uint2*  edges       = (uint2*)alloc((size_t)NE * 8);
    float*  la          = (float*)alloc((size_t)NN * 8);
    float*  cbuf        = (float*)alloc(256);   // me1[0..7], me2[8..11], me3[12..13], vsd[16..55]
    float4* xp          = (float4*)alloc((size_t)NN * 32);
    float4* als1        = (float4*)alloc((size_t)NN * 16);
    float4* ald1        = (float4*)alloc((size_t)NN * 16);
    float*  xw          = (float*)alloc((size_t)NN * 80);
    unsigned short* h2q = (unsigned short*)alloc((size_t)NN * 128);
    float*  als2        = (float*)alloc((size_t)NN * 8);
    float*  ald2        = (float*)alloc((size_t)NN * 8);
    float*  h3          = (float*)alloc((size_t)NN * 4);
    (void)ws_size; (void)in_sizes; (void)n_in; (void)out_size;

    float* me1 = cbuf;
    float* me2 = cbuf + 8;
    float* me3 = cbuf + 12;
    float* vsd = cbuf + 16;

    auto cdiv = [](long long a, long long b) { return (int)((a + b - 1) / b); };
    const int BS = 256;

    // ---- binned CSR build (la fused into binB) ----
    hipMemsetAsync(bucket_cnt, 0, (size_t)(NB + 1) * 4, stream);
    k_binA0<<<NCHUNK, 256, 0, stream>>>(dstv, bucket_cnt);
    k_bscan<<<1, 512, 0, stream>>>(bucket_cnt, bucket_base, bucket_tail);
    k_binA2<<<NCHUNK, 256, 0, stream>>>(srcv, dstv, ea, bucket_tail, binned, dstb);
    k_binB<<<NB, 256, 0, stream>>>(bucket_base, binned, dstb, rowptr, edges, la);

    // ---- all tiny constants in one launch ----
    k_const<<<1, 64, 0, stream>>>(We1, aE1, We2, aE2, We3, aE3, W1, aS1, aD1, cbuf);

    // ================= Layer 1: IN=5, H=4, C=32 (ELU) =================
    k_prep1<<<cdiv(NN, BS), BS, 0, stream>>>(x, vsd, xp, als1, ald1);
    k_agg1<<<cdiv((long long)NN * 4, BS), BS, 0, stream>>>(rowptr, edges, xp,
                                                           (const float*)als1,
                                                           (const float*)ald1, la, me1, xw);

    // ================= Layer 2: IN=128, H=2, C=32 (ELU) =================
    k_l2trans<<<cdiv(NN, 16), 64, 0, stream>>>(xw, W1, b1, W2, aS2, aD2, h2q, als2, ald2);
    k_agg2<<<cdiv((long long)NN * 4, BS), BS, 0, stream>>>(rowptr, edges, h2q, als2, ald2,
                                                           la, me2, b2, W3, h3);

    // ================= Layer 3: IN=64, H=1, C=1 (sigmoid) =================
    k_agg3<<<cdiv(NN, 4), 256, 0, stream>>>(rowptr, edges, h3, aS3, aD3, la, me3,
                                            b3, (float*)d_out);
}